// Round 4
// baseline (815.467 us; speedup 1.0000x reference)
//
#include <hip/hip_runtime.h>
#include <hip/hip_bf16.h>

typedef __bf16 bf16;
typedef __bf16 bf16x4 __attribute__((ext_vector_type(4)));
typedef __bf16 bf16x8 __attribute__((ext_vector_type(8)));
typedef float  f32x4  __attribute__((ext_vector_type(4)));

#define NB 4
#define NC 256
#define NN 4096
#define CQK 32

// ---------------- prep: transpose weights to [c][row] ----------------
__global__ __launch_bounds__(256) void prep_w(
    const float* __restrict__ wq, const float* __restrict__ wk,
    const float* __restrict__ wv, const float* __restrict__ wg,
    float* __restrict__ wT, float* __restrict__ gT) {
  int idx = blockIdx.x * 256 + threadIdx.x;
  if (idx < 256 * 320) {
    int c = idx / 320, r = idx - c * 320;
    float v;
    if (r < 32)      v = wq[r * 256 + c];
    else if (r < 64) v = wk[(r - 32) * 256 + c];
    else             v = wv[(r - 64) * 256 + c];
    wT[idx] = v;
  }
  if (idx < 256 * 256) {
    int c = idx >> 8, r = idx & 255;
    gT[idx] = wg[r * 256 + c];
  }
}

// ---------------- qkv conv: fp32 VALU, weights via uniform loads ----------------
// grid (64 ntiles, 5 chunks, B).  chunk 0 -> q(32)+k(32); chunks 1..4 -> v rows.
__global__ __launch_bounds__(64) void qkv_conv(
    const float* __restrict__ x, const float* __restrict__ wT,
    const float* __restrict__ bq, const float* __restrict__ bk, const float* __restrict__ bv,
    bf16* __restrict__ Q, bf16* __restrict__ K, bf16* __restrict__ Vt) {
  const int n  = blockIdx.x * 64 + threadIdx.x;
  const int ch = blockIdx.y;
  const int b  = blockIdx.z;
  const float* xb = x + (size_t)b * NC * NN;
  float acc[64];
#pragma unroll
  for (int i = 0; i < 64; ++i) acc[i] = 0.f;
  const float* wbase = wT + ch * 64;
  for (int c = 0; c < NC; ++c) {
    float xv = xb[(size_t)c * NN + n];
    const f32x4* w4 = (const f32x4*)(wbase + c * 320);
#pragma unroll
    for (int t = 0; t < 16; ++t) {
      f32x4 w = w4[t];
      acc[t * 4 + 0] += xv * w[0];
      acc[t * 4 + 1] += xv * w[1];
      acc[t * 4 + 2] += xv * w[2];
      acc[t * 4 + 3] += xv * w[3];
    }
  }
  if (ch == 0) {
    bf16* qp = Q + ((size_t)b * NN + n) * CQK;
    bf16* kp = K + ((size_t)b * NN + n) * CQK;
#pragma unroll
    for (int t = 0; t < 4; ++t) {
      bf16x8 vq, vk;
#pragma unroll
      for (int e = 0; e < 8; ++e) {
        int d = t * 8 + e;
        vq[e] = (bf16)(acc[d] + bq[d]);
        vk[e] = (bf16)(acc[32 + d] + bk[d]);
      }
      *(bf16x8*)(qp + t * 8) = vq;
      *(bf16x8*)(kp + t * 8) = vk;
    }
  } else {
    const int r0 = (ch - 1) * 64;
    bf16* vp = Vt + (size_t)b * NC * NN;
#pragma unroll
    for (int du = 0; du < 64; ++du) {
      int r = r0 + du;
      vp[(size_t)r * NN + n] = (bf16)(acc[du] + bv[r]);
    }
  }
}

// ---------------- flash attention ----------------
// Per wave: 16 q-rows, full key sweep, online softmax.
// S^T = mfma(A=K_tile[16x32], B=Qfrag) -> D[j][i]: j=(l>>4)*4+reg, i=l&15.
// PV:  O^T[c][i] += mfma(A=V^T frag, B=P^T) with interleaved key/k-slot map.
__global__ __launch_bounds__(256) void flash_attn(
    const bf16* __restrict__ Q, const bf16* __restrict__ K, const bf16* __restrict__ Vt,
    bf16* __restrict__ Ot) {
  const int lane = threadIdx.x & 63;
  const int wvi  = threadIdx.x >> 6;
  const int b    = blockIdx.y;
  const int i0   = blockIdx.x * 64 + wvi * 16;
  const int lm = lane & 15, lg = lane >> 4;

  const bf16* Qb = Q + (size_t)b * NN * CQK;
  const bf16* Kb = K + (size_t)b * NN * CQK;
  const bf16* Vb = Vt + (size_t)b * NC * NN;

  const bf16x8 qf = *(const bf16x8*)(Qb + (size_t)(i0 + lm) * CQK + lg * 8);

  f32x4 acc[16];
  const f32x4 z4 = {0.f, 0.f, 0.f, 0.f};
#pragma unroll
  for (int i = 0; i < 16; ++i) acc[i] = z4;
  float m_run = -3.0e38f, l_run = 0.f;

  for (int j0 = 0; j0 < NN; j0 += 32) {
    __syncthreads();  // keep the 4 waves temporally aligned for L1 reuse
    bf16x8 kf0 = *(const bf16x8*)(Kb + (size_t)(j0 + lm) * CQK + lg * 8);
    bf16x8 kf1 = *(const bf16x8*)(Kb + (size_t)(j0 + 16 + lm) * CQK + lg * 8);
    f32x4 s0 = __builtin_amdgcn_mfma_f32_16x16x32_bf16(kf0, qf, z4, 0, 0, 0);
    f32x4 s1 = __builtin_amdgcn_mfma_f32_16x16x32_bf16(kf1, qf, z4, 0, 0, 0);

    float tmax = fmaxf(fmaxf(fmaxf(s0[0], s0[1]), fmaxf(s0[2], s0[3])),
                       fmaxf(fmaxf(s1[0], s1[1]), fmaxf(s1[2], s1[3])));
    tmax = fmaxf(tmax, __shfl_xor(tmax, 16, 64));
    tmax = fmaxf(tmax, __shfl_xor(tmax, 32, 64));
    float mnew = fmaxf(m_run, tmax);

    float p0[4], p1[4];
    float psum = 0.f;
#pragma unroll
    for (int r = 0; r < 4; ++r) {
      p0[r] = __expf(s0[r] - mnew);
      p1[r] = __expf(s1[r] - mnew);
      psum += p0[r] + p1[r];
    }
    psum += __shfl_xor(psum, 16, 64);
    psum += __shfl_xor(psum, 32, 64);

    float scale = __expf(m_run - mnew);
    l_run = l_run * scale + psum;
    if (__any(mnew > m_run)) {
#pragma unroll
      for (int cb = 0; cb < 16; ++cb) {
        acc[cb][0] *= scale; acc[cb][1] *= scale;
        acc[cb][2] *= scale; acc[cb][3] *= scale;
      }
    }
    m_run = mnew;

    bf16x8 pb;
#pragma unroll
    for (int r = 0; r < 4; ++r) { pb[r] = (bf16)p0[r]; pb[4 + r] = (bf16)p1[r]; }

    const bf16* vbase = Vb + j0 + lg * 4;
#pragma unroll
    for (int cb = 0; cb < 16; ++cb) {
      const bf16* vp = vbase + (size_t)(cb * 16 + lm) * NN;
      bf16x4 vlo = *(const bf16x4*)(vp);
      bf16x4 vhi = *(const bf16x4*)(vp + 16);
      bf16x8 vf;
#pragma unroll
      for (int e = 0; e < 4; ++e) { vf[e] = vlo[e]; vf[4 + e] = vhi[e]; }
      acc[cb] = __builtin_amdgcn_mfma_f32_16x16x32_bf16(vf, pb, acc[cb], 0, 0, 0);
    }
  }

  float inv = 1.0f / l_run;
  bf16* Ob = Ot + (size_t)b * NC * NN;
#pragma unroll
  for (int cb = 0; cb < 16; ++cb) {
#pragma unroll
    for (int r = 0; r < 4; ++r) {
      Ob[(size_t)(cb * 16 + lg * 4 + r) * NN + i0 + lm] = (bf16)(acc[cb][r] * inv);
    }
  }
}

// ---------------- g conv + bias + residual ----------------
__global__ __launch_bounds__(64) void g_conv(
    const float* __restrict__ x, const bf16* __restrict__ Ot,
    const float* __restrict__ gT, const float* __restrict__ bg,
    float* __restrict__ out) {
  const int n  = blockIdx.x * 64 + threadIdx.x;
  const int ch = blockIdx.y;  // 0..3
  const int b  = blockIdx.z;
  const bf16* ob = Ot + (size_t)b * NC * NN;
  float acc[64];
#pragma unroll
  for (int i = 0; i < 64; ++i) acc[i] = 0.f;
  const float* wbase = gT + ch * 64;
  for (int c = 0; c < NC; ++c) {
    float ov = (float)ob[(size_t)c * NN + n];
    const f32x4* w4 = (const f32x4*)(wbase + c * 256);
#pragma unroll
    for (int t = 0; t < 16; ++t) {
      f32x4 w = w4[t];
      acc[t * 4 + 0] += ov * w[0];
      acc[t * 4 + 1] += ov * w[1];
      acc[t * 4 + 2] += ov * w[2];
      acc[t * 4 + 3] += ov * w[3];
    }
  }
  const int r0 = ch * 64;
#pragma unroll
  for (int du = 0; du < 64; ++du) {
    int r = r0 + du;
    size_t idx = ((size_t)b * NC + r) * NN + n;
    out[idx] = x[idx] + acc[du] + bg[r];
  }
}

extern "C" void kernel_launch(void* const* d_in, const int* in_sizes, int n_in,
                              void* d_out, int out_size, void* d_ws, size_t ws_size,
                              hipStream_t stream) {
  const float* x  = (const float*)d_in[0];
  const float* wq = (const float*)d_in[1];
  const float* bq = (const float*)d_in[2];
  const float* wk = (const float*)d_in[3];
  const float* bk = (const float*)d_in[4];
  const float* wv = (const float*)d_in[5];
  const float* bv = (const float*)d_in[6];
  const float* wg = (const float*)d_in[7];
  const float* bg = (const float*)d_in[8];
  float* out = (float*)d_out;

  char* ws = (char*)d_ws;
  float* wT = (float*)(ws);                                  // 320*256*4   = 327680
  float* gT = (float*)(ws + 327680);                         // 256*256*4   = 262144
  bf16*  Qb = (bf16*)(ws + 589824);                          // 4*4096*32*2 = 1048576
  bf16*  Kb = (bf16*)(ws + 589824 + 1048576);                // 1048576
  bf16*  Vt = (bf16*)(ws + 589824 + 2 * 1048576);            // 4*256*4096*2 = 8388608
  bf16*  Ot = (bf16*)(ws + 589824 + 2 * 1048576 + 8388608);  // 8388608  (total ~18.6 MB)

  hipLaunchKernelGGL(prep_w, dim3(320), dim3(256), 0, stream, wq, wk, wv, wg, wT, gT);
  hipLaunchKernelGGL(qkv_conv, dim3(64, 5, NB), dim3(64), 0, stream,
                     x, wT, bq, bk, bv, Qb, Kb, Vt);
  hipLaunchKernelGGL(flash_attn, dim3(64, NB), dim3(256), 0, stream, Qb, Kb, Vt, Ot);
  hipLaunchKernelGGL(g_conv, dim3(64, 4, NB), dim3(64), 0, stream, x, Ot, gT, bg, out);
}

// Round 6
// 384.435 us; speedup vs baseline: 2.1212x; 2.1212x over previous
//
#include <hip/hip_runtime.h>
#include <hip/hip_bf16.h>

typedef __bf16 bf16;
typedef __bf16 bf16x4 __attribute__((ext_vector_type(4)));
typedef __bf16 bf16x8 __attribute__((ext_vector_type(8)));
typedef float  f32x4  __attribute__((ext_vector_type(4)));

#define NB 4
#define NC 256
#define NN 4096
#define CQK 32

// ---------------- prep: transpose weights to [c][row] ----------------
__global__ __launch_bounds__(256) void prep_w(
    const float* __restrict__ wq, const float* __restrict__ wk,
    const float* __restrict__ wv, const float* __restrict__ wg,
    float* __restrict__ wT, float* __restrict__ gT) {
  int idx = blockIdx.x * 256 + threadIdx.x;
  if (idx < 256 * 320) {
    int c = idx / 320, r = idx - c * 320;
    float v;
    if (r < 32)      v = wq[r * 256 + c];
    else if (r < 64) v = wk[(r - 32) * 256 + c];
    else             v = wv[(r - 64) * 256 + c];
    wT[idx] = v;
  }
  if (idx < 256 * 256) {
    int c = idx >> 8, r = idx & 255;
    gT[idx] = wg[r * 256 + c];
  }
}

// ---------------- qkv conv: fp32 VALU, weights via uniform loads ----------------
__global__ __launch_bounds__(64) void qkv_conv(
    const float* __restrict__ x, const float* __restrict__ wT,
    const float* __restrict__ bq, const float* __restrict__ bk, const float* __restrict__ bv,
    bf16* __restrict__ Q, bf16* __restrict__ K, bf16* __restrict__ Vt) {
  const int n  = blockIdx.x * 64 + threadIdx.x;
  const int ch = blockIdx.y;
  const int b  = blockIdx.z;
  const float* xb = x + (size_t)b * NC * NN;
  float acc[64];
#pragma unroll
  for (int i = 0; i < 64; ++i) acc[i] = 0.f;
  const float* wbase = wT + ch * 64;
  for (int c = 0; c < NC; ++c) {
    float xv = xb[(size_t)c * NN + n];
    const f32x4* w4 = (const f32x4*)(wbase + c * 320);
#pragma unroll
    for (int t = 0; t < 16; ++t) {
      f32x4 w = w4[t];
      acc[t * 4 + 0] += xv * w[0];
      acc[t * 4 + 1] += xv * w[1];
      acc[t * 4 + 2] += xv * w[2];
      acc[t * 4 + 3] += xv * w[3];
    }
  }
  if (ch == 0) {
    bf16* qp = Q + ((size_t)b * NN + n) * CQK;
    bf16* kp = K + ((size_t)b * NN + n) * CQK;
#pragma unroll
    for (int t = 0; t < 4; ++t) {
      bf16x8 vq, vk;
#pragma unroll
      for (int e = 0; e < 8; ++e) {
        int d = t * 8 + e;
        vq[e] = (bf16)(acc[d] + bq[d]);
        vk[e] = (bf16)(acc[32 + d] + bk[d]);
      }
      *(bf16x8*)(qp + t * 8) = vq;
      *(bf16x8*)(kp + t * 8) = vk;
    }
  } else {
    const int r0 = (ch - 1) * 64;
    bf16* vp = Vt + (size_t)b * NC * NN;
#pragma unroll
    for (int du = 0; du < 64; ++du) {
      int r = r0 + du;
      vp[(size_t)r * NN + n] = (bf16)(acc[du] + bv[r]);
    }
  }
}

// ---------------- flash attention v2 ----------------
// 512 threads = 8 waves: wave -> (q-half = wvi>>2 [32 rows], c-slice = (wvi&3)*64).
// Block: 64 q-rows, key sweep in 64-key tiles.
// V tile in LDS, double-buffered 2x32KB, staged via global_load_lds(16B) with
// XOR-swizzled (16B-granule, within 128B row) pre-swizzled global source.
// K tile prefetched into registers (4x bf16x8 per wave).
// S^T = mfma(K,Q): D[key][q]; P stays in-lane for PV B-frag (slot map kb0,kb1 -> khalf).
__global__ __launch_bounds__(512, 2) void flash_attn(
    const bf16* __restrict__ Q, const bf16* __restrict__ K, const bf16* __restrict__ Vt,
    bf16* __restrict__ Ot) {
  extern __shared__ char ldsV[];  // 2 * 32768
  const int tid  = threadIdx.x;
  const int lane = tid & 63, wvi = tid >> 6;
  const int lm = lane & 15, lg = lane >> 4;
  const int b  = blockIdx.y;
  const int i0 = blockIdx.x * 64;
  const int qh = wvi >> 2;        // 0..1
  const int cs = (wvi & 3) * 64;  // c-slice base

  const char* Qg = (const char*)(Q + (size_t)b * NN * CQK);
  const char* Kg = (const char*)(K + (size_t)b * NN * CQK);
  const char* Vg = (const char*)(Vt + (size_t)b * NC * NN);

  // Q fragments (B-operand): q = i0 + qh*32 + qb*16 + lm, d = lg*8..+7
  bf16x8 qf[2];
#pragma unroll
  for (int qb = 0; qb < 2; ++qb)
    qf[qb] = *(const bf16x8*)(Qg + (size_t)(i0 + qh * 32 + qb * 16 + lm) * 64 + lg * 16);

  // V staging slots: inst = ts*8+wvi (32 insts = 256 rows x 128B), row = inst*8 + lane/8
  // LDS chunk (lane&7) sources global chunk (lane&7)^(row&7)  [XOR swizzle]
  const char* vsrc[4];
  int vlds[4];
#pragma unroll
  for (int ts = 0; ts < 4; ++ts) {
    int inst = ts * 8 + wvi;
    int row  = inst * 8 + (lane >> 3);
    vsrc[ts] = Vg + (size_t)row * 8192 + (((lane & 7) ^ (row & 7)) * 16);
    vlds[ts] = inst * 1024;
  }
  // K prefetch pointers: row = kb*16+lm, 16B at d-chunk lg
  const char* ksrc[4];
#pragma unroll
  for (int kb = 0; kb < 4; ++kb)
    ksrc[kb] = Kg + (size_t)(kb * 16 + lm) * 64 + lg * 16;

  // prologue: stage V tile 0, load K tile 0 into regs
#pragma unroll
  for (int ts = 0; ts < 4; ++ts) {
    __builtin_amdgcn_global_load_lds(
        (const __attribute__((address_space(1))) unsigned int*)vsrc[ts],
        (__attribute__((address_space(3))) unsigned int*)(ldsV + vlds[ts]), 16, 0, 0);
    vsrc[ts] += 128;
  }
  bf16x8 kfc[4], kfn[4];
#pragma unroll
  for (int kb = 0; kb < 4; ++kb) { kfc[kb] = *(const bf16x8*)ksrc[kb]; ksrc[kb] += 4096; }

  f32x4 acc[4][2];
  const f32x4 z4 = {0.f, 0.f, 0.f, 0.f};
#pragma unroll
  for (int cb = 0; cb < 4; ++cb)
#pragma unroll
    for (int qb = 0; qb < 2; ++qb) acc[cb][qb] = z4;
  float m_run[2] = {-1e30f, -1e30f}, l_run[2] = {0.f, 0.f};

  __syncthreads();

  for (int t = 0; t < 64; ++t) {
    const int cur = t & 1;
    if (t < 63) {  // stage tile t+1 (other buffer) + prefetch K(t+1) into regs
#pragma unroll
      for (int ts = 0; ts < 4; ++ts) {
        __builtin_amdgcn_global_load_lds(
            (const __attribute__((address_space(1))) unsigned int*)vsrc[ts],
            (__attribute__((address_space(3))) unsigned int*)(ldsV + (cur ^ 1) * 32768 + vlds[ts]),
            16, 0, 0);
        vsrc[ts] += 128;
      }
#pragma unroll
      for (int kb = 0; kb < 4; ++kb) { kfn[kb] = *(const bf16x8*)ksrc[kb]; ksrc[kb] += 4096; }
    }

    // QK^T: s[kb][qb][r] = S[key = t*64 + kb*16 + lg*4 + r][q = qb*16 + lm]
    f32x4 s[4][2];
#pragma unroll
    for (int kb = 0; kb < 4; ++kb)
#pragma unroll
      for (int qb = 0; qb < 2; ++qb)
        s[kb][qb] = __builtin_amdgcn_mfma_f32_16x16x32_bf16(kfc[kb], qf[qb], z4, 0, 0, 0);

    // online softmax (defer-max THR=8) + P pack
    bf16x8 pb[2][2];
#pragma unroll
    for (int qb = 0; qb < 2; ++qb) {
      float tmax = s[0][qb][0];
#pragma unroll
      for (int kb = 0; kb < 4; ++kb)
#pragma unroll
        for (int r = 0; r < 4; ++r) tmax = fmaxf(tmax, s[kb][qb][r]);
      tmax = fmaxf(tmax, __shfl_xor(tmax, 16, 64));
      tmax = fmaxf(tmax, __shfl_xor(tmax, 32, 64));
      if (__any(tmax > m_run[qb] + 8.f)) {
        float mnew = fmaxf(m_run[qb], tmax);
        float sc   = __expf(m_run[qb] - mnew);
        l_run[qb] *= sc;
#pragma unroll
        for (int cb = 0; cb < 4; ++cb) {
          acc[cb][qb][0] *= sc; acc[cb][qb][1] *= sc;
          acc[cb][qb][2] *= sc; acc[cb][qb][3] *= sc;
        }
        m_run[qb] = mnew;
      }
      float ps = 0.f;
      float pf[4][4];
#pragma unroll
      for (int kb = 0; kb < 4; ++kb)
#pragma unroll
        for (int r = 0; r < 4; ++r) {
          pf[kb][r] = __expf(s[kb][qb][r] - m_run[qb]);
          ps += pf[kb][r];
        }
      ps += __shfl_xor(ps, 16, 64);
      ps += __shfl_xor(ps, 32, 64);
      l_run[qb] += ps;
#pragma unroll
      for (int kh = 0; kh < 2; ++kh) {
        bf16x8 p;
#pragma unroll
        for (int r = 0; r < 4; ++r) {
          p[r]     = (bf16)pf[kh * 2][r];
          p[4 + r] = (bf16)pf[kh * 2 + 1][r];
        }
        pb[qb][kh] = p;
      }
    }

    // PV: A = V-slice frag from swizzled LDS, B = pb
    const char* vb  = ldsV + cur * 32768;
    const int   lg1 = lg & 1, lg2 = lg >> 1;
#pragma unroll
    for (int cb = 0; cb < 4; ++cb) {
      int row = cs + cb * 16 + lm;
      int rx  = row & 7;
      int rb  = row * 128 + lg1 * 8;
#pragma unroll
      for (int kh = 0; kh < 2; ++kh) {
        bf16x4 vlo = *(const bf16x4*)(vb + rb + (((kh * 4) + lg2) ^ rx) * 16);
        bf16x4 vhi = *(const bf16x4*)(vb + rb + (((kh * 4) + 2 + lg2) ^ rx) * 16);
        bf16x8 vf;
#pragma unroll
        for (int e = 0; e < 4; ++e) { vf[e] = vlo[e]; vf[4 + e] = vhi[e]; }
#pragma unroll
        for (int qb = 0; qb < 2; ++qb)
          acc[cb][qb] = __builtin_amdgcn_mfma_f32_16x16x32_bf16(vf, pb[qb][kh], acc[cb][qb], 0, 0, 0);
      }
    }

    __syncthreads();  // drains vmcnt (next V tile staged) + all waves done with buf[cur]
#pragma unroll
    for (int kb = 0; kb < 4; ++kb) kfc[kb] = kfn[kb];
  }

  bf16* Ob = Ot + (size_t)b * NC * NN;
  float inv[2] = {1.f / l_run[0], 1.f / l_run[1]};
#pragma unroll
  for (int cb = 0; cb < 4; ++cb)
#pragma unroll
    for (int qb = 0; qb < 2; ++qb)
#pragma unroll
      for (int r = 0; r < 4; ++r)
        Ob[(size_t)(cs + cb * 16 + lg * 4 + r) * NN + i0 + qh * 32 + qb * 16 + lm] =
            (bf16)(acc[cb][qb][r] * inv[qb]);
}

// ---------------- g conv + bias + residual ----------------
__global__ __launch_bounds__(64) void g_conv(
    const float* __restrict__ x, const bf16* __restrict__ Ot,
    const float* __restrict__ gT, const float* __restrict__ bg,
    float* __restrict__ out) {
  const int n  = blockIdx.x * 64 + threadIdx.x;
  const int ch = blockIdx.y;  // 0..3
  const int b  = blockIdx.z;
  const bf16* ob = Ot + (size_t)b * NC * NN;
  float acc[64];
#pragma unroll
  for (int i = 0; i < 64; ++i) acc[i] = 0.f;
  const float* wbase = gT + ch * 64;
  for (int c = 0; c < NC; ++c) {
    float ov = (float)ob[(size_t)c * NN + n];
    const f32x4* w4 = (const f32x4*)(wbase + c * 256);
#pragma unroll
    for (int t = 0; t < 16; ++t) {
      f32x4 w = w4[t];
      acc[t * 4 + 0] += ov * w[0];
      acc[t * 4 + 1] += ov * w[1];
      acc[t * 4 + 2] += ov * w[2];
      acc[t * 4 + 3] += ov * w[3];
    }
  }
  const int r0 = ch * 64;
#pragma unroll
  for (int du = 0; du < 64; ++du) {
    int r = r0 + du;
    size_t idx = ((size_t)b * NC + r) * NN + n;
    out[idx] = x[idx] + acc[du] + bg[r];
  }
}

extern "C" void kernel_launch(void* const* d_in, const int* in_sizes, int n_in,
                              void* d_out, int out_size, void* d_ws, size_t ws_size,
                              hipStream_t stream) {
  const float* x  = (const float*)d_in[0];
  const float* wq = (const float*)d_in[1];
  const float* bq = (const float*)d_in[2];
  const float* wk = (const float*)d_in[3];
  const float* bk = (const float*)d_in[4];
  const float* wv = (const float*)d_in[5];
  const float* bv = (const float*)d_in[6];
  const float* wg = (const float*)d_in[7];
  const float* bg = (const float*)d_in[8];
  float* out = (float*)d_out;

  char* ws = (char*)d_ws;
  float* wT = (float*)(ws);                                  // 320*256*4   = 327680
  float* gT = (float*)(ws + 327680);                         // 256*256*4   = 262144
  bf16*  Qb = (bf16*)(ws + 589824);                          // 4*4096*32*2 = 1048576
  bf16*  Kb = (bf16*)(ws + 589824 + 1048576);                // 1048576
  bf16*  Vt = (bf16*)(ws + 589824 + 2 * 1048576);            // 4*256*4096*2 = 8388608
  bf16*  Ot = (bf16*)(ws + 589824 + 2 * 1048576 + 8388608);  // 8388608  (total ~18.6 MB)

  hipLaunchKernelGGL(prep_w, dim3(320), dim3(256), 0, stream, wq, wk, wv, wg, wT, gT);
  hipLaunchKernelGGL(qkv_conv, dim3(64, 5, NB), dim3(64), 0, stream,
                     x, wT, bq, bk, bv, Qb, Kb, Vt);
  hipLaunchKernelGGL(flash_attn, dim3(64, NB), dim3(512), 65536, stream, Qb, Kb, Vt, Ot);
  hipLaunchKernelGGL(g_conv, dim3(64, 4, NB), dim3(64), 0, stream, x, Ot, gT, bg, out);
}

// Round 7
// 257.294 us; speedup vs baseline: 3.1694x; 1.4941x over previous
//
#include <hip/hip_runtime.h>
#include <hip/hip_bf16.h>

typedef __bf16 bf16;
typedef __bf16 bf16x4 __attribute__((ext_vector_type(4)));
typedef __bf16 bf16x8 __attribute__((ext_vector_type(8)));
typedef float  f32x4  __attribute__((ext_vector_type(4)));

#define NB 4
#define NC 256
#define NN 4096
#define CQK 32

// ---------------- prep: transpose weights to [c][row] ----------------
__global__ __launch_bounds__(256) void prep_w(
    const float* __restrict__ wq, const float* __restrict__ wk,
    const float* __restrict__ wv, const float* __restrict__ wg,
    float* __restrict__ wT, float* __restrict__ gT) {
  int idx = blockIdx.x * 256 + threadIdx.x;
  if (idx < 256 * 320) {
    int c = idx / 320, r = idx - c * 320;
    float v;
    if (r < 32)      v = wq[r * 256 + c];
    else if (r < 64) v = wk[(r - 32) * 256 + c];
    else             v = wv[(r - 64) * 256 + c];
    wT[idx] = v;
  }
  if (idx < 256 * 256) {
    int c = idx >> 8, r = idx & 255;
    gT[idx] = wg[r * 256 + c];
  }
}

// ---------------- qkv conv: fp32 VALU, 16 outputs/thread ----------------
// grid (NN/256, 20, B); chunk ch: rows ch*16..+15 of [q(32) k(32) v(256)].
__global__ __launch_bounds__(256) void qkv_conv(
    const float* __restrict__ x, const float* __restrict__ wT,
    const float* __restrict__ bq, const float* __restrict__ bk, const float* __restrict__ bv,
    bf16* __restrict__ Q, bf16* __restrict__ K, bf16* __restrict__ Vt) {
  const int n  = blockIdx.x * 256 + threadIdx.x;
  const int ch = blockIdx.y;  // 0..19
  const int b  = blockIdx.z;
  const float* xb = x + (size_t)b * NC * NN;
  float acc[16];
#pragma unroll
  for (int i = 0; i < 16; ++i) acc[i] = 0.f;
  const float* wbase = wT + ch * 16;
  for (int c = 0; c < NC; ++c) {
    float xv = xb[(size_t)c * NN + n];
    const f32x4* w4 = (const f32x4*)(wbase + (size_t)c * 320);
#pragma unroll
    for (int t = 0; t < 4; ++t) {
      f32x4 w = w4[t];
      acc[t * 4 + 0] += xv * w[0];
      acc[t * 4 + 1] += xv * w[1];
      acc[t * 4 + 2] += xv * w[2];
      acc[t * 4 + 3] += xv * w[3];
    }
  }
  if (ch < 2) {
    const int d0 = ch * 16;
    bf16* qp = Q + ((size_t)b * NN + n) * CQK + d0;
#pragma unroll
    for (int t = 0; t < 2; ++t) {
      bf16x8 v;
#pragma unroll
      for (int e = 0; e < 8; ++e) v[e] = (bf16)(acc[t * 8 + e] + bq[d0 + t * 8 + e]);
      *(bf16x8*)(qp + t * 8) = v;
    }
  } else if (ch < 4) {
    const int d0 = (ch - 2) * 16;
    bf16* kp = K + ((size_t)b * NN + n) * CQK + d0;
#pragma unroll
    for (int t = 0; t < 2; ++t) {
      bf16x8 v;
#pragma unroll
      for (int e = 0; e < 8; ++e) v[e] = (bf16)(acc[t * 8 + e] + bk[d0 + t * 8 + e]);
      *(bf16x8*)(kp + t * 8) = v;
    }
  } else {
    const int r0 = (ch - 4) * 16;
    bf16* vp = Vt + (size_t)b * NC * NN;
#pragma unroll
    for (int e = 0; e < 16; ++e)
      vp[(size_t)(r0 + e) * NN + n] = (bf16)(acc[e] + bv[r0 + e]);
  }
}

// ---------------- flash attention v3 ----------------
// 256 threads = 4 waves; wave wvi owns 16 q-rows (i0 + wvi*16) x FULL 256 channels.
// No softmax/QK duplication. V tile (64 keys x 256 ch) in LDS, double-buffered,
// staged via global_load_lds(16B) with XOR-swizzled pre-swizzled global source.
// K tile prefetched to regs one tile ahead.
__global__ __launch_bounds__(256) void flash_attn(
    const bf16* __restrict__ Q, const bf16* __restrict__ K, const bf16* __restrict__ Vt,
    bf16* __restrict__ Ot) {
  extern __shared__ char ldsV[];  // 2 * 32768
  const int tid  = threadIdx.x;
  const int lane = tid & 63, wvi = tid >> 6;
  const int lm = lane & 15, lg = lane >> 4;
  const int b  = blockIdx.y;
  const int i0 = blockIdx.x * 64;

  const char* Qg = (const char*)(Q + (size_t)b * NN * CQK);
  const char* Kg = (const char*)(K + (size_t)b * NN * CQK);
  const char* Vg = (const char*)(Vt + (size_t)b * NC * NN);

  // Q fragment (B-operand): q = i0 + wvi*16 + lm, d = lg*8..+7
  const bf16x8 qf = *(const bf16x8*)(Qg + (size_t)(i0 + wvi * 16 + lm) * 64 + lg * 16);

  // V staging: 32 insts x (64 lanes x 16B) = 256 rows x 128B; inst = ts*4 + wvi.
  // LDS[row][chunk] = global[row][chunk ^ (row&7)]  (16B chunks)
  const char* vsrc[8];
  int vlds[8];
#pragma unroll
  for (int ts = 0; ts < 8; ++ts) {
    int inst = ts * 4 + wvi;
    int row  = inst * 8 + (lane >> 3);
    vsrc[ts] = Vg + (size_t)row * 8192 + (((lane & 7) ^ (row & 7)) * 16);
    vlds[ts] = inst * 1024;
  }
  // K prefetch: row = kb*16 + lm, 16B chunk lg
  const char* ksrc[4];
#pragma unroll
  for (int kb = 0; kb < 4; ++kb)
    ksrc[kb] = Kg + (size_t)(kb * 16 + lm) * 64 + lg * 16;

  // prologue
#pragma unroll
  for (int ts = 0; ts < 8; ++ts) {
    __builtin_amdgcn_global_load_lds(
        (const __attribute__((address_space(1))) unsigned int*)vsrc[ts],
        (__attribute__((address_space(3))) unsigned int*)(ldsV + vlds[ts]), 16, 0, 0);
    vsrc[ts] += 128;
  }
  bf16x8 kfc[4], kfn[4];
#pragma unroll
  for (int kb = 0; kb < 4; ++kb) { kfc[kb] = *(const bf16x8*)ksrc[kb]; ksrc[kb] += 4096; }

  f32x4 acc[16];
  const f32x4 z4 = {0.f, 0.f, 0.f, 0.f};
#pragma unroll
  for (int cb = 0; cb < 16; ++cb) acc[cb] = z4;
  float m_run = -1e30f, l_run = 0.f;

  __syncthreads();

  for (int t = 0; t < 64; ++t) {
    const int cur = t & 1;
    if (t < 63) {
#pragma unroll
      for (int ts = 0; ts < 8; ++ts) {
        __builtin_amdgcn_global_load_lds(
            (const __attribute__((address_space(1))) unsigned int*)vsrc[ts],
            (__attribute__((address_space(3))) unsigned int*)(ldsV + (cur ^ 1) * 32768 + vlds[ts]),
            16, 0, 0);
        vsrc[ts] += 128;
      }
#pragma unroll
      for (int kb = 0; kb < 4; ++kb) { kfn[kb] = *(const bf16x8*)ksrc[kb]; ksrc[kb] += 4096; }
    }

    // QK^T: s[kb][r] = S[key = t*64 + kb*16 + lg*4 + r][q = i0 + wvi*16 + lm]
    f32x4 s[4];
#pragma unroll
    for (int kb = 0; kb < 4; ++kb)
      s[kb] = __builtin_amdgcn_mfma_f32_16x16x32_bf16(kfc[kb], qf, z4, 0, 0, 0);

    // online softmax (defer-max THR=8)
    float tmax = s[0][0];
#pragma unroll
    for (int kb = 0; kb < 4; ++kb)
#pragma unroll
      for (int r = 0; r < 4; ++r) tmax = fmaxf(tmax, s[kb][r]);
    tmax = fmaxf(tmax, __shfl_xor(tmax, 16, 64));
    tmax = fmaxf(tmax, __shfl_xor(tmax, 32, 64));
    if (__any(tmax > m_run + 8.f)) {
      float mnew = fmaxf(m_run, tmax);
      float sc   = __expf(m_run - mnew);
      l_run *= sc;
#pragma unroll
      for (int cb = 0; cb < 16; ++cb) {
        acc[cb][0] *= sc; acc[cb][1] *= sc;
        acc[cb][2] *= sc; acc[cb][3] *= sc;
      }
      m_run = mnew;
    }
    float pf[4][4];
    float ps = 0.f;
#pragma unroll
    for (int kb = 0; kb < 4; ++kb)
#pragma unroll
      for (int r = 0; r < 4; ++r) {
        pf[kb][r] = __expf(s[kb][r] - m_run);
        ps += pf[kb][r];
      }
    ps += __shfl_xor(ps, 16, 64);
    ps += __shfl_xor(ps, 32, 64);
    l_run += ps;

    // P pack: element e of pb[kh] -> key kh*32 + (e<4 ? lg*4+e : 16+lg*4+(e-4))
    bf16x8 pb[2];
#pragma unroll
    for (int kh = 0; kh < 2; ++kh) {
      bf16x8 p;
#pragma unroll
      for (int r = 0; r < 4; ++r) {
        p[r]     = (bf16)pf[kh * 2][r];
        p[4 + r] = (bf16)pf[kh * 2 + 1][r];
      }
      pb[kh] = p;
    }

    // PV over full 256 channels
    const char* vb  = ldsV + cur * 32768;
    const int   lg1 = lg & 1, lg2 = lg >> 1;
#pragma unroll
    for (int cb = 0; cb < 16; ++cb) {
      int row = cb * 16 + lm;
      int rx  = row & 7;
      int rb  = row * 128 + lg1 * 8;
#pragma unroll
      for (int kh = 0; kh < 2; ++kh) {
        bf16x4 vlo = *(const bf16x4*)(vb + rb + (((kh * 4) + lg2) ^ rx) * 16);
        bf16x4 vhi = *(const bf16x4*)(vb + rb + (((kh * 4) + 2 + lg2) ^ rx) * 16);
        bf16x8 vf;
#pragma unroll
        for (int e = 0; e < 4; ++e) { vf[e] = vlo[e]; vf[4 + e] = vhi[e]; }
        acc[cb] = __builtin_amdgcn_mfma_f32_16x16x32_bf16(vf, pb[kh], acc[cb], 0, 0, 0);
      }
    }

    __syncthreads();  // all waves done with buf[cur]; next tile staged
#pragma unroll
    for (int kb = 0; kb < 4; ++kb) kfc[kb] = kfn[kb];
  }

  bf16* Ob = Ot + (size_t)b * NC * NN;
  const float inv = 1.0f / l_run;
#pragma unroll
  for (int cb = 0; cb < 16; ++cb)
#pragma unroll
    for (int r = 0; r < 4; ++r)
      Ob[(size_t)(cb * 16 + lg * 4 + r) * NN + i0 + wvi * 16 + lm] =
          (bf16)(acc[cb][r] * inv);
}

// ---------------- g conv + bias + residual: 16 outputs/thread ----------------
__global__ __launch_bounds__(256) void g_conv(
    const float* __restrict__ x, const bf16* __restrict__ Ot,
    const float* __restrict__ gT, const float* __restrict__ bg,
    float* __restrict__ out) {
  const int n  = blockIdx.x * 256 + threadIdx.x;
  const int ch = blockIdx.y;  // 0..15
  const int b  = blockIdx.z;
  const bf16* ob = Ot + (size_t)b * NC * NN;
  float acc[16];
#pragma unroll
  for (int i = 0; i < 16; ++i) acc[i] = 0.f;
  const float* wbase = gT + ch * 16;
  for (int c = 0; c < NC; ++c) {
    float ov = (float)ob[(size_t)c * NN + n];
    const f32x4* w4 = (const f32x4*)(wbase + (size_t)c * 256);
#pragma unroll
    for (int t = 0; t < 4; ++t) {
      f32x4 w = w4[t];
      acc[t * 4 + 0] += ov * w[0];
      acc[t * 4 + 1] += ov * w[1];
      acc[t * 4 + 2] += ov * w[2];
      acc[t * 4 + 3] += ov * w[3];
    }
  }
  const int r0 = ch * 16;
#pragma unroll
  for (int e = 0; e < 16; ++e) {
    int r = r0 + e;
    size_t idx = ((size_t)b * NC + r) * NN + n;
    out[idx] = x[idx] + acc[e] + bg[r];
  }
}

extern "C" void kernel_launch(void* const* d_in, const int* in_sizes, int n_in,
                              void* d_out, int out_size, void* d_ws, size_t ws_size,
                              hipStream_t stream) {
  const float* x  = (const float*)d_in[0];
  const float* wq = (const float*)d_in[1];
  const float* bq = (const float*)d_in[2];
  const float* wk = (const float*)d_in[3];
  const float* bk = (const float*)d_in[4];
  const float* wv = (const float*)d_in[5];
  const float* bv = (const float*)d_in[6];
  const float* wg = (const float*)d_in[7];
  const float* bg = (const float*)d_in[8];
  float* out = (float*)d_out;

  char* ws = (char*)d_ws;
  float* wT = (float*)(ws);                                  // 320*256*4   = 327680
  float* gT = (float*)(ws + 327680);                         // 256*256*4   = 262144
  bf16*  Qb = (bf16*)(ws + 589824);                          // 4*4096*32*2 = 1048576
  bf16*  Kb = (bf16*)(ws + 589824 + 1048576);                // 1048576
  bf16*  Vt = (bf16*)(ws + 589824 + 2 * 1048576);            // 4*256*4096*2 = 8388608
  bf16*  Ot = (bf16*)(ws + 589824 + 2 * 1048576 + 8388608);  // 8388608  (total ~18.6 MB)

  hipLaunchKernelGGL(prep_w, dim3(320), dim3(256), 0, stream, wq, wk, wv, wg, wT, gT);
  hipLaunchKernelGGL(qkv_conv, dim3(16, 20, NB), dim3(256), 0, stream,
                     x, wT, bq, bk, bv, Qb, Kb, Vt);
  hipLaunchKernelGGL(flash_attn, dim3(64, NB), dim3(256), 65536, stream, Qb, Kb, Vt, Ot);
  hipLaunchKernelGGL(g_conv, dim3(16, 16, NB), dim3(256), 0, stream, x, Ot, gT, bg, out);
}

// Round 8
// 230.019 us; speedup vs baseline: 3.5452x; 1.1186x over previous
//
#include <hip/hip_runtime.h>
#include <hip/hip_bf16.h>

typedef __bf16 bf16;
typedef __bf16 bf16x4 __attribute__((ext_vector_type(4)));
typedef __bf16 bf16x8 __attribute__((ext_vector_type(8)));
typedef float  f32x4  __attribute__((ext_vector_type(4)));
typedef float  f32x16 __attribute__((ext_vector_type(16)));

#define NB 4
#define NC 256
#define NN 4096
#define LOG2E 1.44269504088896f

#define GLL16(src, dst) __builtin_amdgcn_global_load_lds( \
    (const __attribute__((address_space(1))) unsigned int*)(src), \
    (__attribute__((address_space(3))) unsigned int*)(dst), 16, 0, 0)

// ---------------- prep: cast weights to bf16 (row-major [out][in]) ----------------
__global__ __launch_bounds__(256) void prep_cast(
    const float* __restrict__ wq, const float* __restrict__ wk,
    const float* __restrict__ wv, const float* __restrict__ wg,
    bf16* __restrict__ Wbf, bf16* __restrict__ Gbf) {
  int idx = blockIdx.x * 256 + threadIdx.x;
  if (idx < 81920) {  // 320 rows x 256
    float v;
    if (idx < 8192)       v = wq[idx];
    else if (idx < 16384) v = wk[idx - 8192];
    else                  v = wv[idx - 16384];
    Wbf[idx] = (bf16)v;
  } else if (idx < 81920 + 65536) {
    int g = idx - 81920;
    Gbf[g] = (bf16)wg[g];
  }
}

// ---------------- xpose: x[b][c][n] f32 -> xT[b][n][c] bf16 ----------------
__global__ __launch_bounds__(256) void xpose(
    const float* __restrict__ x, bf16* __restrict__ xT) {
  __shared__ bf16 ldsT[64 * 64];
  const int tid = threadIdx.x;
  const int n0 = blockIdx.x * 64, c0 = blockIdx.y * 64, b = blockIdx.z;
  const int nl = tid & 63;
#pragma unroll
  for (int p = 0; p < 16; ++p) {
    int cl = p * 4 + (tid >> 6);
    float v = x[((size_t)b * NC + c0 + cl) * NN + n0 + nl];
    ldsT[nl * 64 + (cl ^ nl)] = (bf16)v;
  }
  __syncthreads();
  const int n2 = tid >> 2, q = tid & 3;
  bf16x8 v0, v1;
#pragma unroll
  for (int j = 0; j < 8; ++j) {
    v0[j] = ldsT[n2 * 64 + ((q * 16 + j) ^ n2)];
    v1[j] = ldsT[n2 * 64 + ((q * 16 + 8 + j) ^ n2)];
  }
  bf16* dst = xT + ((size_t)b * NN + n0 + n2) * NC + c0 + q * 16;
  *(bf16x8*)dst = v0;
  *(bf16x8*)(dst + 8) = v1;
}

// ---------------- opose: Ot[b][c][n] bf16 -> OtT[b][n][c] bf16 ----------------
__global__ __launch_bounds__(256) void opose(
    const bf16* __restrict__ Ot, bf16* __restrict__ OtT) {
  __shared__ bf16 ldsT[64 * 64];
  const int tid = threadIdx.x;
  const int n0 = blockIdx.x * 64, c0 = blockIdx.y * 64, b = blockIdx.z;
  const int nl = tid & 63;
#pragma unroll
  for (int p = 0; p < 16; ++p) {
    int cl = p * 4 + (tid >> 6);
    ldsT[nl * 64 + (cl ^ nl)] = Ot[((size_t)b * NC + c0 + cl) * NN + n0 + nl];
  }
  __syncthreads();
  const int n2 = tid >> 2, q = tid & 3;
  bf16x8 v0, v1;
#pragma unroll
  for (int j = 0; j < 8; ++j) {
    v0[j] = ldsT[n2 * 64 + ((q * 16 + j) ^ n2)];
    v1[j] = ldsT[n2 * 64 + ((q * 16 + 8 + j) ^ n2)];
  }
  bf16* dst = OtT + ((size_t)b * NN + n0 + n2) * NC + c0 + q * 16;
  *(bf16x8*)dst = v0;
  *(bf16x8*)(dst + 8) = v1;
}

// ---------------- qkv GEMM: [320x256] x xT^T -> Q[n][32]*log2e, K[n][32], Vt[c][n] ----------------
// grid (64 n-tiles, 5 m-tiles, B), 256 thr. B staged in LDS (swizzled), A (weights) in regs.
__global__ __launch_bounds__(256, 4) void qkv_gemm(
    const bf16* __restrict__ Wbf, const bf16* __restrict__ xT,
    const float* __restrict__ bq, const float* __restrict__ bk, const float* __restrict__ bv,
    bf16* __restrict__ Q, bf16* __restrict__ K, bf16* __restrict__ Vt) {
  __shared__ char lds[40960];  // 32KB B-tile + 8KB transpose scratch
  const int tid = threadIdx.x, lane = tid & 63, wv = tid >> 6;
  const int lm = lane & 15, lg = lane >> 4;
  const int n0 = blockIdx.x * 64, mt = blockIdx.y, b = blockIdx.z;
  const int m0 = mt * 64;

  bf16x8 af[8];
  const bf16* wrow = Wbf + (size_t)(m0 + wv * 16 + lm) * 256;
#pragma unroll
  for (int s = 0; s < 8; ++s) af[s] = *(const bf16x8*)(wrow + s * 32 + lg * 8);

  const char* xb = (const char*)(xT + ((size_t)b * NN + n0) * NC);
#pragma unroll
  for (int i = 0; i < 8; ++i) {
    int inst = i * 4 + wv;
    int nl = inst * 2 + (lane >> 5);
    int ch = lane & 31;
    GLL16(xb + (size_t)nl * 512 + ((ch ^ (nl & 7)) * 16), lds + inst * 1024);
  }
  __syncthreads();

  f32x4 acc[4];
  const f32x4 z4 = {0.f, 0.f, 0.f, 0.f};
#pragma unroll
  for (int nb = 0; nb < 4; ++nb) acc[nb] = z4;
#pragma unroll
  for (int s = 0; s < 8; ++s) {
#pragma unroll
    for (int nb = 0; nb < 4; ++nb) {
      int nl = nb * 16 + lm;
      bf16x8 bfr = *(const bf16x8*)(lds + nl * 512 + (((s * 4 + lg) ^ (nl & 7)) * 16));
      acc[nb] = __builtin_amdgcn_mfma_f32_16x16x32_bf16(af[s], bfr, acc[nb], 0, 0, 0);
    }
  }

  if (mt == 0) {  // q/k rows: transpose via LDS to [n][32]
    bf16* lds2 = (bf16*)(lds + 32768);
    __syncthreads();  // all B reads done before scratch reuse ordering w.r.t. reads below
#pragma unroll
    for (int nb = 0; nb < 4; ++nb) {
      int nl = nb * 16 + lm;
#pragma unroll
      for (int rr = 0; rr < 4; ++rr) {
        int m = wv * 16 + lg * 4 + rr;
        float val = (m < 32) ? (acc[nb][rr] + bq[m]) * LOG2E : acc[nb][rr] + bk[m - 32];
        lds2[m * 64 + (nl ^ m)] = (bf16)val;
      }
    }
    __syncthreads();
    const int n2 = tid >> 2, q = tid & 3;
    bf16x8 v0, v1;
#pragma unroll
    for (int j = 0; j < 8; ++j) {
      int m = q * 16 + j;
      v0[j] = lds2[m * 64 + (n2 ^ m)];
      int m2 = q * 16 + 8 + j;
      v1[j] = lds2[m2 * 64 + (n2 ^ m2)];
    }
    bf16* dst = (q < 2) ? (Q + ((size_t)b * NN + n0 + n2) * 32 + q * 16)
                        : (K + ((size_t)b * NN + n0 + n2) * 32 + (q - 2) * 16);
    *(bf16x8*)dst = v0;
    *(bf16x8*)(dst + 8) = v1;
  } else {  // v rows -> Vt[c][n]
#pragma unroll
    for (int nb = 0; nb < 4; ++nb) {
#pragma unroll
      for (int rr = 0; rr < 4; ++rr) {
        int vrow = m0 - 64 + wv * 16 + lg * 4 + rr;
        Vt[((size_t)b * NC + vrow) * NN + n0 + nb * 16 + lm] = (bf16)(acc[nb][rr] + bv[vrow]);
      }
    }
  }
}

// ---------------- flash attention v4: 32x32x16 MFMA ----------------
// 512 thr = 8 waves = 2 q-groups x 4 c-slices. Wave: 32 q-rows x 64 channels.
// QK: S=mfma(K,Q): lane holds 32 key-scores for ONE q -> in-lane softmax (1 shfl).
// PV: A=V (LDS, XOR-swizzled), B=P in-lane. Q pre-scaled by log2e -> exp2.
__global__ __launch_bounds__(512, 2) void flash_attn(
    const bf16* __restrict__ Q, const bf16* __restrict__ K, const bf16* __restrict__ Vt,
    bf16* __restrict__ Ot) {
  __shared__ char ldsV[65536];
  const int tid = threadIdx.x;
  const int lane = tid & 63, wvi = tid >> 6;
  const int l31 = lane & 31, h = lane >> 5;
  const int qg = wvi >> 2, cs = (wvi & 3) * 64;
  const int b = blockIdx.y;
  const int i0 = blockIdx.x * 64;

  const char* Qg = (const char*)(Q + (size_t)b * NN * 32);
  const char* Kg = (const char*)(K + (size_t)b * NN * 32);
  const char* Vg = (const char*)(Vt + (size_t)b * NC * NN);

  // Q frags: B-operand, q = i0+qg*32+l31, d-half dh
  bf16x8 qf[2];
#pragma unroll
  for (int dh = 0; dh < 2; ++dh)
    qf[dh] = *(const bf16x8*)(Qg + (size_t)(i0 + qg * 32 + l31) * 64 + dh * 32 + h * 16);

  // V staging: 32 insts x 1024B; LDS[row][c16] = G[row][c16 ^ (row&7)]
  const char* vsrc[4];
  int vlds[4];
#pragma unroll
  for (int ts = 0; ts < 4; ++ts) {
    int inst = ts * 8 + wvi;
    int row = inst * 8 + (lane >> 3);
    vsrc[ts] = Vg + (size_t)row * 8192 + (((lane & 7) ^ (row & 7)) * 16);
    vlds[ts] = inst * 1024;
  }
  // K frag sources: idx g*2+dh
  const char* ksrc[4];
#pragma unroll
  for (int g = 0; g < 2; ++g)
#pragma unroll
    for (int dh = 0; dh < 2; ++dh)
      ksrc[g * 2 + dh] = Kg + (size_t)(g * 32 + l31) * 64 + dh * 32 + h * 16;

#pragma unroll
  for (int ts = 0; ts < 4; ++ts) { GLL16(vsrc[ts], ldsV + vlds[ts]); vsrc[ts] += 128; }
  bf16x8 kfc[4], kfn[4];
#pragma unroll
  for (int i = 0; i < 4; ++i) { kfc[i] = *(const bf16x8*)ksrc[i]; ksrc[i] += 4096; }

  const f32x16 z16 = {0.f,0.f,0.f,0.f,0.f,0.f,0.f,0.f,0.f,0.f,0.f,0.f,0.f,0.f,0.f,0.f};
  f32x16 acc0 = z16, acc1 = z16;
  float m_run = -1e30f, l_lane = 0.f;

  __syncthreads();

  for (int t = 0; t < 64; ++t) {
    const int cur = t & 1;
    if (t < 63) {
#pragma unroll
      for (int ts = 0; ts < 4; ++ts) {
        GLL16(vsrc[ts], ldsV + (cur ^ 1) * 32768 + vlds[ts]);
        vsrc[ts] += 128;
      }
#pragma unroll
      for (int i = 0; i < 4; ++i) { kfn[i] = *(const bf16x8*)ksrc[i]; ksrc[i] += 4096; }
    }

    // QK^T: s0 = keys g0 (t*64+0..31), s1 = keys g1 (+32..63); lane q = i0+qg*32+l31
    f32x16 s0 = __builtin_amdgcn_mfma_f32_32x32x16_bf16(kfc[0], qf[0], z16, 0, 0, 0);
    s0 = __builtin_amdgcn_mfma_f32_32x32x16_bf16(kfc[1], qf[1], s0, 0, 0, 0);
    f32x16 s1 = __builtin_amdgcn_mfma_f32_32x32x16_bf16(kfc[2], qf[0], z16, 0, 0, 0);
    s1 = __builtin_amdgcn_mfma_f32_32x32x16_bf16(kfc[3], qf[1], s1, 0, 0, 0);

    // in-lane max tree (32 vals) + 1 shfl
    float tm[8];
#pragma unroll
    for (int i = 0; i < 8; ++i)
      tm[i] = fmaxf(fmaxf(s0[i], s0[i + 8]), fmaxf(s1[i], s1[i + 8]));
#pragma unroll
    for (int i = 0; i < 4; ++i) tm[i] = fmaxf(tm[i], tm[i + 4]);
    float tmax = fmaxf(fmaxf(tm[0], tm[1]), fmaxf(tm[2], tm[3]));
    tmax = fmaxf(tmax, __shfl_xor(tmax, 32, 64));

    if (__any(tmax > m_run + 8.f)) {
      float mnew = fmaxf(m_run, tmax);
      float sc = exp2f(m_run - mnew);
      l_lane *= sc;
#pragma unroll
      for (int r = 0; r < 16; ++r) { acc0[r] *= sc; acc1[r] *= sc; }
      m_run = mnew;
    }
#pragma unroll
    for (int r = 0; r < 16; ++r) {
      s0[r] = exp2f(s0[r] - m_run);
      s1[r] = exp2f(s1[r] - m_run);
    }
    float sm[8];
#pragma unroll
    for (int i = 0; i < 8; ++i) sm[i] = (s0[i] + s0[i + 8]) + (s1[i] + s1[i + 8]);
#pragma unroll
    for (int i = 0; i < 4; ++i) sm[i] += sm[i + 4];
    l_lane += (sm[0] + sm[1]) + (sm[2] + sm[3]);

    // P pack: pb[step][e] = p(key = step*16 + 4h + (e&3) + 8*(e>>2))
    bf16x8 pb[4];
#pragma unroll
    for (int s1b = 0; s1b < 2; ++s1b)
#pragma unroll
      for (int e = 0; e < 8; ++e) {
        pb[s1b][e]     = (bf16)s0[8 * s1b + 4 * (e >> 2) + (e & 3)];
        pb[2 + s1b][e] = (bf16)s1[8 * s1b + 4 * (e >> 2) + (e & 3)];
      }

    // PV: 2 ch-groups x 4 k-steps
    const char* vb = ldsV + cur * 32768;
    const int rx = lane & 7;
    const int rowb = (cs + l31) * 128 + 8 * h;
#pragma unroll
    for (int chg = 0; chg < 2; ++chg) {
      const char* vrow = vb + rowb + chg * 4096;
#pragma unroll
      for (int st = 0; st < 4; ++st) {
        bf16x4 vlo = *(const bf16x4*)(vrow + (((2 * st) ^ rx) * 16));
        bf16x4 vhi = *(const bf16x4*)(vrow + (((2 * st + 1) ^ rx) * 16));
        bf16x8 vf;
#pragma unroll
        for (int e = 0; e < 4; ++e) { vf[e] = vlo[e]; vf[4 + e] = vhi[e]; }
        if (chg == 0) acc0 = __builtin_amdgcn_mfma_f32_32x32x16_bf16(vf, pb[st], acc0, 0, 0, 0);
        else          acc1 = __builtin_amdgcn_mfma_f32_32x32x16_bf16(vf, pb[st], acc1, 0, 0, 0);
      }
    }

    __syncthreads();
#pragma unroll
    for (int i = 0; i < 4; ++i) kfc[i] = kfn[i];
  }

  float l_tot = l_lane + __shfl_xor(l_lane, 32, 64);
  float inv = 1.0f / l_tot;
  bf16* Ob = Ot + (size_t)b * NC * NN;
  const int qcol = i0 + qg * 32 + l31;
#pragma unroll
  for (int reg = 0; reg < 16; ++reg) {
    int kk = (reg & 3) + 8 * (reg >> 2) + 4 * h;
    Ob[(size_t)(cs + kk) * NN + qcol]      = (bf16)(acc0[reg] * inv);
    Ob[(size_t)(cs + 32 + kk) * NN + qcol] = (bf16)(acc1[reg] * inv);
  }
}

// ---------------- g GEMM + bias + residual: out = x + Gbf x O ----------------
__global__ __launch_bounds__(256, 4) void g_gemm(
    const bf16* __restrict__ Gbf, const bf16* __restrict__ OtT,
    const float* __restrict__ x, const float* __restrict__ bg,
    float* __restrict__ out) {
  __shared__ char lds[32768];
  const int tid = threadIdx.x, lane = tid & 63, wv = tid >> 6;
  const int lm = lane & 15, lg = lane >> 4;
  const int n0 = blockIdx.x * 64, mt = blockIdx.y, b = blockIdx.z;
  const int m0 = mt * 64;

  bf16x8 af[8];
  const bf16* wrow = Gbf + (size_t)(m0 + wv * 16 + lm) * 256;
#pragma unroll
  for (int s = 0; s < 8; ++s) af[s] = *(const bf16x8*)(wrow + s * 32 + lg * 8);

  const char* ob = (const char*)(OtT + ((size_t)b * NN + n0) * NC);
#pragma unroll
  for (int i = 0; i < 8; ++i) {
    int inst = i * 4 + wv;
    int nl = inst * 2 + (lane >> 5);
    int ch = lane & 31;
    GLL16(ob + (size_t)nl * 512 + ((ch ^ (nl & 7)) * 16), lds + inst * 1024);
  }
  __syncthreads();

  f32x4 acc[4];
  const f32x4 z4 = {0.f, 0.f, 0.f, 0.f};
#pragma unroll
  for (int nb = 0; nb < 4; ++nb) acc[nb] = z4;
#pragma unroll
  for (int s = 0; s < 8; ++s) {
#pragma unroll
    for (int nb = 0; nb < 4; ++nb) {
      int nl = nb * 16 + lm;
      bf16x8 bfr = *(const bf16x8*)(lds + nl * 512 + (((s * 4 + lg) ^ (nl & 7)) * 16));
      acc[nb] = __builtin_amdgcn_mfma_f32_16x16x32_bf16(af[s], bfr, acc[nb], 0, 0, 0);
    }
  }
#pragma unroll
  for (int nb = 0; nb < 4; ++nb) {
#pragma unroll
    for (int rr = 0; rr < 4; ++rr) {
      int row = m0 + wv * 16 + lg * 4 + rr;
      size_t idx = ((size_t)b * NC + row) * NN + n0 + nb * 16 + lm;
      out[idx] = x[idx] + acc[nb][rr] + bg[row];
    }
  }
}

extern "C" void kernel_launch(void* const* d_in, const int* in_sizes, int n_in,
                              void* d_out, int out_size, void* d_ws, size_t ws_size,
                              hipStream_t stream) {
  const float* x  = (const float*)d_in[0];
  const float* wq = (const float*)d_in[1];
  const float* bq = (const float*)d_in[2];
  const float* wk = (const float*)d_in[3];
  const float* bk = (const float*)d_in[4];
  const float* wv = (const float*)d_in[5];
  const float* bv = (const float*)d_in[6];
  const float* wg = (const float*)d_in[7];
  const float* bg = (const float*)d_in[8];
  float* out = (float*)d_out;

  char* ws = (char*)d_ws;
  bf16* Wbf = (bf16*)(ws);                    // 163840
  bf16* Gbf = (bf16*)(ws + 163840);           // 131072 -> 294912
  bf16* Qb  = (bf16*)(ws + 294912);           // 1048576 -> 1343488
  bf16* Kb  = (bf16*)(ws + 1343488);          // 1048576 -> 2392064
  bf16* xT  = (bf16*)(ws + 2392064);          // 8388608 -> 10780672 (reused as Ot)
  bf16* Vt  = (bf16*)(ws + 10780672);         // 8388608 -> 19169280 (reused as OtT)
  bf16* Ot  = xT;                              // xT dead after qkv_gemm
  bf16* OtT = Vt;                              // Vt dead after flash_attn

  hipLaunchKernelGGL(prep_cast, dim3(576), dim3(256), 0, stream, wq, wk, wv, wg, Wbf, Gbf);
  hipLaunchKernelGGL(xpose, dim3(64, 4, NB), dim3(256), 0, stream, x, xT);
  hipLaunchKernelGGL(qkv_gemm, dim3(64, 5, NB), dim3(256), 0, stream,
                     Wbf, xT, bq, bk, bv, Qb, Kb, Vt);
  hipLaunchKernelGGL(flash_attn, dim3(64, NB), dim3(512), 0, stream, Qb, Kb, Vt, Ot);
  hipLaunchKernelGGL(opose, dim3(64, 4, NB), dim3(256), 0, stream, Ot, OtT);
  hipLaunchKernelGGL(g_gemm, dim3(64, 4, NB), dim3(256), 0, stream, Gbf, OtT, x, bg, out);
}